// Round 12
// baseline (312.237 us; speedup 1.0000x reference)
//
#include <hip/hip_runtime.h>
#include <cstdint>
#include <cstddef>

#define DIM   512
#define QKD   128
#define HID   1024
#define SEQ   4096
#define BAT   4
#define TOK   (BAT*SEQ)
#define NPAD  2304   // hidden+qk fused N padded to 9*256

typedef float f32x4 __attribute__((ext_vector_type(4)));
typedef int   i32x4 __attribute__((ext_vector_type(4)));
typedef int   i32x8 __attribute__((ext_vector_type(8)));

__device__ __forceinline__ float silu_f(float x) { return x / (1.f + __expf(-x)); }

__device__ __forceinline__ unsigned char f2e4(float f) {
    int v = __builtin_amdgcn_cvt_pk_fp8_f32(f, 0.f, 0, false);
    return (unsigned char)(v & 0xff);
}
__device__ __forceinline__ unsigned f2e4x4(float a, float b, float c, float d) {
    int w = __builtin_amdgcn_cvt_pk_fp8_f32(a, b, 0, false);
    w = __builtin_amdgcn_cvt_pk_fp8_f32(c, d, w, true);
    return (unsigned)w;
}
__device__ __forceinline__ float e42f(unsigned char b) {
    return __builtin_amdgcn_cvt_f32_fp8((int)b, 0);
}

__device__ __forceinline__ void load16_lds(const void* gp, void* lp) {
    __builtin_amdgcn_global_load_lds(
        (const __attribute__((address_space(1))) unsigned int*)gp,
        (__attribute__((address_space(3))) unsigned int*)lp,
        16, 0, 0);
}

#define WAITV6() asm volatile("s_waitcnt vmcnt(6)" ::: "memory")
#define WAITV0() asm volatile("s_waitcnt vmcnt(0)" ::: "memory")
#define FENCE()  do { asm volatile("" ::: "memory"); __builtin_amdgcn_sched_barrier(0); } while (0)

#define MFMA8(af, bf, c) __builtin_amdgcn_mfma_scale_f32_16x16x128_f8f6f4( \
    af, bf, c, 0, 0, 0, 0x7F7F7F7F, 0, 0x7F7F7F7F)

// ---------------- LayerNorm: fp32 x -> fp8 normed ----------------
__global__ __launch_bounds__(256) void ln_kernel(
    const float* __restrict__ x, const float* __restrict__ sc,
    const float* __restrict__ bi, unsigned char* __restrict__ out)
{
    const int lane = threadIdx.x & 63, wid = threadIdx.x >> 6;
    const int row  = blockIdx.x * 4 + wid;
    const float4* xr = (const float4*)(x + (size_t)row * DIM);
    float4 a = xr[lane], b = xr[64 + lane];
    float s = a.x + a.y + a.z + a.w + b.x + b.y + b.z + b.w;
    float q = a.x*a.x + a.y*a.y + a.z*a.z + a.w*a.w
            + b.x*b.x + b.y*b.y + b.z*b.z + b.w*b.w;
#pragma unroll
    for (int m = 1; m < 64; m <<= 1) { s += __shfl_xor(s, m); q += __shfl_xor(q, m); }
    const float mean = s * (1.f / DIM);
    const float var  = q * (1.f / DIM) - mean * mean;
    const float rs   = rsqrtf(var + 1e-5f);
    float4 s0 = ((const float4*)sc)[lane], s1 = ((const float4*)sc)[64 + lane];
    float4 b0 = ((const float4*)bi)[lane], b1 = ((const float4*)bi)[64 + lane];
    unsigned wlo = f2e4x4((a.x - mean) * rs * s0.x + b0.x,
                          (a.y - mean) * rs * s0.y + b0.y,
                          (a.z - mean) * rs * s0.z + b0.z,
                          (a.w - mean) * rs * s0.w + b0.w);
    unsigned whi = f2e4x4((b.x - mean) * rs * s1.x + b1.x,
                          (b.y - mean) * rs * s1.y + b1.y,
                          (b.z - mean) * rs * s1.z + b1.z,
                          (b.w - mean) * rs * s1.w + b1.w);
    unsigned char* orow = out + (size_t)row * DIM;
    *(unsigned*)(orow + 4 * lane)       = wlo;
    *(unsigned*)(orow + 256 + 4 * lane) = whi;
}

// ---------------- transpose-cast fp32 (RxC) -> fp8 (CxR), x16 ----------------
__global__ __launch_bounds__(256) void tcast_f2e4_kernel(
    const float* __restrict__ in, unsigned char* __restrict__ out, int R, int C)
{
    __shared__ float t[32][33];
    const int tx = threadIdx.x & 31, ty = threadIdx.x >> 5;
    const int c0 = blockIdx.x * 32, r0 = blockIdx.y * 32;
#pragma unroll
    for (int i = 0; i < 4; ++i)
        t[ty + i * 8][tx] = in[(size_t)(r0 + ty + i * 8) * C + c0 + tx];
    __syncthreads();
#pragma unroll
    for (int i = 0; i < 4; ++i)
        out[(size_t)(c0 + ty + i * 8) * R + r0 + tx] = f2e4(t[tx][ty + i * 8] * 16.f);
}

// ---------------- zero-fill (16B/thread) ----------------
__global__ __launch_bounds__(256) void zero_kernel(float4* __restrict__ p)
{
    p[blockIdx.x * 256 + threadIdx.x] = float4{0.f, 0.f, 0.f, 0.f};
}

// ---------------- fallback: out = x ----------------
__global__ __launch_bounds__(256) void copy_kernel(
    const float* __restrict__ in, float* __restrict__ out, int n4)
{
    int i = blockIdx.x * 256 + threadIdx.x;
    int stride = gridDim.x * 256;
    for (; i < n4; i += stride)
        ((float4*)out)[i] = ((const float4*)in)[i];
}

// ============ single-buffer 128x128 kernel — kept for sim (K=128, NT=1) ======
template<int EPI, int NX>
__global__ __launch_bounds__(256) void gemm8(
    const unsigned char* __restrict__ A, const unsigned char* __restrict__ B,
    int K, long strAz, long strBz, long strOz,
    const float* __restrict__ f0, const float* __restrict__ f1,
    const float* __restrict__ f2, const float* __restrict__ f3,
    const float* __restrict__ f4, const float* __restrict__ f5,
    unsigned char* __restrict__ gate,
    unsigned char* __restrict__ o0, unsigned char* __restrict__ o1,
    unsigned char* __restrict__ o2,
    float* __restrict__ fo, float scale)
{
    __shared__ unsigned char lds[32768];
    const int tid = threadIdx.x;
    const int d  = blockIdx.x + NX * blockIdx.y;
    const int qd = d >> 3;
    const int m0 = ((d & 7) + 8 * (qd / NX)) * 128;
    const int n0 = (qd % NX) * 128;
    const int z  = blockIdx.z;
    A += (size_t)z * strAz;  B += (size_t)z * strBz;
    const int lane = tid & 63, wid = tid >> 6;
    const int wm   = (wid & 1) * 64, wn = (wid >> 1) * 64;
    const int l15  = lane & 15, quad = lane >> 4;

    f32x4 acc[4][4] = {};

    const int srow = tid >> 3, sseg = tid & 7;
    const int gseg = sseg ^ (srow & 7);
    const unsigned char* gA = A + (size_t)(m0 + srow) * K + gseg * 16;
    const unsigned char* gB = B + (size_t)(n0 + srow) * K + gseg * 16;
    unsigned char* lA = lds + (size_t)tid * 16;
    unsigned char* lB = lds + 16384 + (size_t)tid * 16;

    const int olo = (((quad << 1) ^ (l15 & 7)) << 4);
    const int ohi = olo ^ 16;

    for (int kt = 0; kt < K; kt += 128) {
#pragma unroll
        for (int i = 0; i < 4; ++i)
            load16_lds(gA + (size_t)i * 32 * K + kt, lA + i * 4096);
#pragma unroll
        for (int i = 0; i < 4; ++i)
            load16_lds(gB + (size_t)i * 32 * K + kt, lB + i * 4096);
        __syncthreads();
        i32x4 alo[4], ahi[4], blo[4], bhi[4];
#pragma unroll
        for (int mi = 0; mi < 4; ++mi) {
            const unsigned char* p = lds + (wm + mi * 16 + l15) * 128;
            alo[mi] = *(const i32x4*)(p + olo); ahi[mi] = *(const i32x4*)(p + ohi);
        }
#pragma unroll
        for (int ni = 0; ni < 4; ++ni) {
            const unsigned char* p = lds + 16384 + (wn + ni * 16 + l15) * 128;
            blo[ni] = *(const i32x4*)(p + olo); bhi[ni] = *(const i32x4*)(p + ohi);
        }
#pragma unroll
        for (int mi = 0; mi < 4; ++mi) {
            i32x8 af = __builtin_shufflevector(alo[mi], ahi[mi], 0,1,2,3,4,5,6,7);
#pragma unroll
            for (int ni = 0; ni < 4; ++ni) {
                i32x8 bf = __builtin_shufflevector(blo[ni], bhi[ni], 0,1,2,3,4,5,6,7);
                acc[mi][ni] = MFMA8(af, bf, acc[mi][ni]);
            }
        }
        __syncthreads();
    }

#pragma unroll
    for (int mi = 0; mi < 4; ++mi)
#pragma unroll
    for (int ni = 0; ni < 4; ++ni) {
        const int grow0 = m0 + wm + mi * 16 + quad * 4;
        const int gcol  = n0 + wn + ni * 16 + l15;
        if constexpr (EPI == 1) {
            unsigned char* Ao = o0 + (size_t)z * strOz;
#pragma unroll
            for (int r = 0; r < 4; ++r) {
                float t = fmaxf(acc[mi][ni][r], 0.f) * 0.0625f;
                Ao[(size_t)(grow0 + r) * SEQ + gcol] = f2e4(t * t);
            }
        }
    }
}

// ====== pipelined GEMM: BM=256 x BN=128, BK=128, 8 waves, 3 LDS buffers ======
// Exact R2 structure (HW-proven 4x; VGPR=88, ledger proven against emitted
// stream). Used for EPI3 (out-GEMM; N=512 needs 128-wide tiles for grid size).
template<int EPI, int NX>
__global__ __launch_bounds__(512, 2) void gemm8p(
    const unsigned char* __restrict__ A, const unsigned char* __restrict__ B,
    int K, long strAz, long strBz, long strOz,
    const float* __restrict__ f0, const float* __restrict__ f1,
    const float* __restrict__ f2, const float* __restrict__ f3,
    const float* __restrict__ f4, const float* __restrict__ f5,
    unsigned char* __restrict__ gate,
    unsigned char* __restrict__ o0, unsigned char* __restrict__ o1,
    unsigned char* __restrict__ o2,
    float* __restrict__ fo, float scale)
{
    __shared__ unsigned char lds[3 * 49152];   // per buf: A 32 KiB | B 16 KiB
    const int tid = threadIdx.x;
    const int d  = blockIdx.x + NX * blockIdx.y;
    const int qd = d >> 3;
    const int m0 = ((d & 7) + 8 * (qd / NX)) * 256;
    const int n0 = (qd % NX) * 128;
    const int z  = blockIdx.z;
    A += (size_t)z * strAz;  B += (size_t)z * strBz;
    const int lane = tid & 63, wid = tid >> 6;
    const int wm   = (wid & 3) * 64, wn = (wid >> 2) * 64;
    const int l15  = lane & 15, quad = lane >> 4;

    f32x4 acc[4][4] = {};

    const int srow = tid >> 3, sseg = tid & 7;
    const int gseg = sseg ^ (srow & 7);
    const unsigned char* gAs = A + (size_t)(m0 + srow) * K + gseg * 16;
    const unsigned char* gBs = B + (size_t)(n0 + srow) * K + gseg * 16;

    const int olo = (((quad << 1) ^ (l15 & 7)) << 4);
    const int ohi = olo ^ 16;

    const int NT = K >> 7;

    auto STAGE = [&](int t, int buf) {
        const size_t ko = (size_t)t << 7;
        unsigned char* lb = lds + buf * 49152 + tid * 16;
#pragma unroll
        for (int i = 0; i < 4; ++i)
            load16_lds(gAs + (size_t)(i * 64) * K + ko, lb + i * 8192);
#pragma unroll
        for (int i = 0; i < 2; ++i)
            load16_lds(gBs + (size_t)(i * 64) * K + ko, lb + 32768 + i * 8192);
    };

    auto COMPUTE = [&](int buf) {
        const unsigned char* la = lds + buf * 49152;
        const unsigned char* lb = la + 32768;
        i32x4 alo[4], ahi[4], blo[4], bhi[4];
#pragma unroll
        for (int mi = 0; mi < 4; ++mi) {
            const unsigned char* p = la + (size_t)(wm + mi * 16 + l15) * 128;
            alo[mi] = *(const i32x4*)(p + olo); ahi[mi] = *(const i32x4*)(p + ohi);
        }
#pragma unroll
        for (int ni = 0; ni < 4; ++ni) {
            const unsigned char* p = lb + (size_t)(wn + ni * 16 + l15) * 128;
            blo[ni] = *(const i32x4*)(p + olo); bhi[ni] = *(const i32x4*)(p + ohi);
        }
#pragma unroll
        for (int mi = 0; mi < 4; ++mi) {
            i32x8 af = __builtin_shufflevector(alo[mi], ahi[mi], 0,1,2,3,4,5,6,7);
#pragma unroll
            for (int ni = 0; ni < 4; ++ni) {
                i32x8 bf = __builtin_shufflevector(blo[ni], bhi[ni], 0,1,2,3,4,5,6,7);
                acc[mi][ni] = MFMA8(af, bf, acc[mi][ni]);
            }
        }
    };

    STAGE(0, 0);
    if (NT > 1) { STAGE(1, 1); WAITV6(); }
    else        {              WAITV0(); }
    __builtin_amdgcn_s_barrier();
    FENCE();

    int cbuf = 0, sbuf = 2;
    for (int t = 0; t < NT; ++t) {
        if (t + 2 < NT) STAGE(t + 2, sbuf);
        COMPUTE(cbuf);
        if (t + 1 < NT) {
            if (t + 2 < NT) WAITV6(); else WAITV0();
            __builtin_amdgcn_s_barrier();
            FENCE();
        }
        cbuf = (cbuf == 2) ? 0 : cbuf + 1;
        sbuf = (sbuf == 2) ? 0 : sbuf + 1;
    }

#pragma unroll
    for (int mi = 0; mi < 4; ++mi)
#pragma unroll
    for (int ni = 0; ni < 4; ++ni) {
        const int grow0 = m0 + wm + mi * 16 + quad * 4;
        const int gcol  = n0 + wn + ni * 16 + l15;
        if constexpr (EPI == 3) {
#pragma unroll
            for (int r = 0; r < 4; ++r)
                fo[(size_t)(grow0 + r) * DIM + gcol] =
                    acc[mi][ni][r] * scale + f0[gcol] + f1[(size_t)(grow0 + r) * DIM + gcol];
        }
    }
}

// ====== gemm11: 256x256 2-buffer single-sync GEMM (R11 structure, proven) ====
// Wave tile 128x64, flat front-loaded fragment reads (R2's COMPUTE shape ->
// partial-lgkmcnt MFMA/port overlap), ONE plain __syncthreads per tile,
// issue-early STAGE. No manual vmcnt. Proven on A@v (R11: 80.2 -> <69 us).
// R12: EPI 0 added (hidden+qk fused, N padded to 2304 = 9*256; gcol>=2176
// columns are compute-only garbage, stores guarded).
template<int EPI, int NX>
__global__ __launch_bounds__(512, 2) void gemm11(
    const unsigned char* __restrict__ A, const unsigned char* __restrict__ B,
    int K, long strAz, long strBz, long strOz,
    const float* __restrict__ f0, const float* __restrict__ f1,
    const float* __restrict__ f2, const float* __restrict__ f3,
    const float* __restrict__ f4, const float* __restrict__ f5,
    unsigned char* __restrict__ gate,
    unsigned char* __restrict__ o0, unsigned char* __restrict__ o1,
    unsigned char* __restrict__ o2,
    float scale)
{
    __shared__ unsigned char lds[2 * 65536];   // per buf: A 32 KiB | B 32 KiB
    const int tid = threadIdx.x;
    const int d  = blockIdx.x + NX * blockIdx.y;
    const int qd = d >> 3;
    const int m0 = ((d & 7) + 8 * (qd / NX)) * 256;
    const int n0 = (qd % NX) * 256;
    const int z  = blockIdx.z;
    A += (size_t)z * strAz;  B += (size_t)z * strBz;
    const int lane = tid & 63, wid = tid >> 6;
    const int wm   = (wid & 1) * 128, wn = (wid >> 1) * 64;
    const int l15  = lane & 15, quad = lane >> 4;

    f32x4 acc[8][4] = {};

    const int srow = tid >> 3, sseg = tid & 7;
    const int gseg = sseg ^ (srow & 7);
    const unsigned char* gAs = A + (size_t)(m0 + srow) * K + gseg * 16;
    const unsigned char* gBs = B + (size_t)(n0 + srow) * K + gseg * 16;

    const int olo = (((quad << 1) ^ (l15 & 7)) << 4);
    const int ohi = olo ^ 16;

    const int NT = K >> 7;

    auto STAGE = [&](int t, int buf) {
        const size_t ko = (size_t)t << 7;
        unsigned char* lb = lds + buf * 65536 + tid * 16;
#pragma unroll
        for (int i = 0; i < 4; ++i)
            load16_lds(gAs + (size_t)(i * 64) * K + ko, lb + i * 8192);
#pragma unroll
        for (int i = 0; i < 4; ++i)
            load16_lds(gBs + (size_t)(i * 64) * K + ko, lb + 32768 + i * 8192);
    };

    STAGE(0, 0);
    __syncthreads();                    // tile 0 resident (one-time exposure)

    for (int t = 0; t < NT; ++t) {
        if (t + 1 < NT) { STAGE(t + 1, (t + 1) & 1); FENCE(); }
        const unsigned char* la = lds + (t & 1) * 65536;
        const unsigned char* lb = la + 32768;
        i32x4 alo[8], ahi[8], blo[4], bhi[4];
#pragma unroll
        for (int mi = 0; mi < 8; ++mi) {
            const unsigned char* p = la + (size_t)(wm + mi * 16 + l15) * 128;
            alo[mi] = *(const i32x4*)(p + olo); ahi[mi] = *(const i32x4*)(p + ohi);
        }
#pragma unroll
        for (int ni = 0; ni < 4; ++ni) {
            const unsigned char* p = lb + (size_t)(wn + ni * 16 + l15) * 128;
            blo[ni] = *(const i32x4*)(p + olo); bhi[ni] = *(const i32x4*)(p + ohi);
        }
#pragma unroll
        for (int mi = 0; mi < 8; ++mi) {
            i32x8 af = __builtin_shufflevector(alo[mi], ahi[mi], 0,1,2,3,4,5,6,7);
#pragma unroll
            for (int ni = 0; ni < 4; ++ni) {
                i32x8 bf = __builtin_shufflevector(blo[ni], bhi[ni], 0,1,2,3,4,5,6,7);
                acc[mi][ni] = MFMA8(af, bf, acc[mi][ni]);
            }
        }
        if (t + 1 < NT) __syncthreads();
    }

    // C/D layout: col = lane&15, row = quad*4 + reg
#pragma unroll
    for (int mi = 0; mi < 8; ++mi)
#pragma unroll
    for (int ni = 0; ni < 4; ++ni) {
        const int grow0 = m0 + wm + mi * 16 + quad * 4;
        const int gcol  = n0 + wn + ni * 16 + l15;
        if constexpr (EPI == 0) {
            if (gcol < HID) {
                const int b = grow0 >> 12, rloc = grow0 & (SEQ - 1);
                unsigned w = f2e4x4(silu_f(acc[mi][ni][0] * 0.0625f + f0[gcol]),
                                    silu_f(acc[mi][ni][1] * 0.0625f + f0[gcol]),
                                    silu_f(acc[mi][ni][2] * 0.0625f + f0[gcol]),
                                    silu_f(acc[mi][ni][3] * 0.0625f + f0[gcol]));
                *(unsigned*)(o0 + (size_t)b * HID * SEQ + (size_t)gcol * SEQ + rloc) = w;
            } else if (gcol < 2048) {
#pragma unroll
                for (int r = 0; r < 4; ++r)
                    gate[(size_t)(grow0 + r) * HID + (gcol - HID)] =
                        f2e4(silu_f(acc[mi][ni][r] * 0.0625f + f0[gcol]));
            } else if (gcol < 2176) {
                const int c = gcol - 2048;
#pragma unroll
                for (int r = 0; r < 4; ++r) {
                    float zf = silu_f(acc[mi][ni][r] * 0.0625f + f1[c]);
                    o1[(size_t)(grow0 + r) * QKD + c] = f2e4((zf * f2[c] + f4[c]) * 64.f);
                    o2[(size_t)(grow0 + r) * QKD + c] = f2e4((zf * f3[c] + f5[c]) * 64.f);
                }
            }   // else: padded garbage columns — no store
        } else if constexpr (EPI == 2) {
            unsigned char* gz = gate + (size_t)z * strOz;
            unsigned char* vo = o0 + (size_t)z * strOz;
#pragma unroll
            for (int r = 0; r < 4; ++r) {
                float g = e42f(gz[(size_t)(grow0 + r) * HID + gcol]);
                vo[(size_t)(grow0 + r) * HID + gcol] = f2e4(acc[mi][ni][r] * scale * g);
            }
        }
    }
}

extern "C" void kernel_launch(void* const* d_in, const int* in_sizes, int n_in,
                              void* d_out, int out_size, void* d_ws, size_t ws_size,
                              hipStream_t stream) {
    const float* x     = (const float*)d_in[0];
    const float* nsc   = (const float*)d_in[1];
    const float* nbi   = (const float*)d_in[2];
    const float* Wh    = (const float*)d_in[3];
    const float* bh    = (const float*)d_in[4];
    const float* Wqk   = (const float*)d_in[5];
    const float* bqk   = (const float*)d_in[6];
    const float* gamma = (const float*)d_in[7];
    const float* beta  = (const float*)d_in[8];
    const float* Wout  = (const float*)d_in[9];
    const float* bout  = (const float*)d_in[10];
    float* out = (float*)d_out;

    uint8_t* ws = (uint8_t*)d_ws;
    size_t off = 0;
    auto alloc = [&](size_t n) { uint8_t* p = ws + off; off += (n + 255) & ~(size_t)255; return p; };
    unsigned char* normed8 = (unsigned char*)alloc((size_t)TOK * DIM);
    unsigned char* Wc8     = (unsigned char*)alloc((size_t)NPAD * DIM);   // [WhT;WqkT;pad] x16
    unsigned char* Wout8   = (unsigned char*)alloc((size_t)DIM * HID);    // x16
    unsigned char* vT8     = (unsigned char*)alloc((size_t)BAT * HID * SEQ);
    unsigned char* gbuf    = (unsigned char*)alloc((size_t)TOK * HID);    // gate fp8
    unsigned char* q8      = (unsigned char*)alloc((size_t)TOK * QKD);    // x64
    unsigned char* k8      = (unsigned char*)alloc((size_t)TOK * QKD);    // x64
    unsigned char* Ab8     = (unsigned char*)alloc((size_t)BAT * SEQ * SEQ); // x2^40
    unsigned char* vg8     = (unsigned char*)alloc((size_t)TOK * HID);    // x2^28

    if (ws_size < off) {
        copy_kernel<<<4096, 256, 0, stream>>>(x, out, TOK * DIM / 4);
        return;
    }

    ln_kernel<<<TOK / 4, 256, 0, stream>>>(x, nsc, nbi, normed8);
    tcast_f2e4_kernel<<<dim3(2048 / 32, DIM / 32), 256, 0, stream>>>(Wh, Wc8, DIM, 2048);
    tcast_f2e4_kernel<<<dim3(QKD / 32, DIM / 32), 256, 0, stream>>>(
        Wqk, Wc8 + (size_t)2048 * DIM, DIM, QKD);
    // zero the pad rows 2176..2303 (64 KiB) so staged garbage is benign
    zero_kernel<<<16, 256, 0, stream>>>((float4*)(Wc8 + (size_t)2176 * DIM));
    tcast_f2e4_kernel<<<dim3(DIM / 32, HID / 32), 256, 0, stream>>>(Wout, Wout8, HID, DIM);

    // hidden + qk fused: M=16384, N=2304 (9 x 256, last 128 cols pad), K=512
    gemm11<0, 9><<<dim3(9, TOK / 256), 512, 0, stream>>>(
        normed8, Wc8, DIM, 0, 0, 0,
        bh, bqk, gamma, gamma + QKD, beta, beta + QKD,
        gbuf, vT8, q8, k8, 0.f);

    // sim: K = 128 (single slab, no pipeline) -> keep 128x128 kernel
    gemm8<1, 32><<<dim3(SEQ / 128, SEQ / 128, BAT), 256, 0, stream>>>(
        q8, k8, QKD, (long)SEQ * QKD, (long)SEQ * QKD, (long)SEQ * SEQ,
        nullptr, nullptr, nullptr, nullptr, nullptr, nullptr,
        nullptr, Ab8, nullptr, nullptr, nullptr, 0.f);

    // A@v: M=4096/z, N=1024, K=4096 (NT=32), z-batched; vg8 = acc*2^-12*gate
    gemm11<2, 4><<<dim3(HID / 256, SEQ / 256, BAT), 512, 0, stream>>>(
        Ab8, vT8, SEQ, (long)SEQ * SEQ, (long)HID * SEQ, (long)SEQ * HID,
        nullptr, nullptr, nullptr, nullptr, nullptr, nullptr,
        gbuf, vg8, nullptr, nullptr, 0x1p-12f);

    // out: M=16384, N=512, K=1024 (NT=8); out = acc*2^-32 + b_out + x
    gemm8p<3, 4><<<dim3(DIM / 128, TOK / 256), 512, 0, stream>>>(
        vg8, Wout8, HID, 0, 0, 0,
        bout, x, nullptr, nullptr, nullptr, nullptr,
        nullptr, nullptr, nullptr, nullptr, out, 0x1p-32f);
}

// Round 13
// 274.426 us; speedup vs baseline: 1.1378x; 1.1378x over previous
//
#include <hip/hip_runtime.h>
#include <cstdint>
#include <cstddef>

#define DIM   512
#define QKD   128
#define HID   1024
#define SEQ   4096
#define BAT   4
#define TOK   (BAT*SEQ)

typedef float f32x4 __attribute__((ext_vector_type(4)));
typedef int   i32x4 __attribute__((ext_vector_type(4)));
typedef int   i32x8 __attribute__((ext_vector_type(8)));

__device__ __forceinline__ float silu_f(float x) { return x / (1.f + __expf(-x)); }

__device__ __forceinline__ unsigned char f2e4(float f) {
    int v = __builtin_amdgcn_cvt_pk_fp8_f32(f, 0.f, 0, false);
    return (unsigned char)(v & 0xff);
}
__device__ __forceinline__ unsigned f2e4x4(float a, float b, float c, float d) {
    int w = __builtin_amdgcn_cvt_pk_fp8_f32(a, b, 0, false);
    w = __builtin_amdgcn_cvt_pk_fp8_f32(c, d, w, true);
    return (unsigned)w;
}
__device__ __forceinline__ float e42f(unsigned char b) {
    return __builtin_amdgcn_cvt_f32_fp8((int)b, 0);
}

__device__ __forceinline__ void load16_lds(const void* gp, void* lp) {
    __builtin_amdgcn_global_load_lds(
        (const __attribute__((address_space(1))) unsigned int*)gp,
        (__attribute__((address_space(3))) unsigned int*)lp,
        16, 0, 0);
}

#define WAITV6() asm volatile("s_waitcnt vmcnt(6)" ::: "memory")
#define WAITV0() asm volatile("s_waitcnt vmcnt(0)" ::: "memory")
#define FENCE()  do { asm volatile("" ::: "memory"); __builtin_amdgcn_sched_barrier(0); } while (0)

#define MFMA8(af, bf, c) __builtin_amdgcn_mfma_scale_f32_16x16x128_f8f6f4( \
    af, bf, c, 0, 0, 0, 0x7F7F7F7F, 0, 0x7F7F7F7F)

// ---------------- LayerNorm: fp32 x -> fp8 normed ----------------
__global__ __launch_bounds__(256) void ln_kernel(
    const float* __restrict__ x, const float* __restrict__ sc,
    const float* __restrict__ bi, unsigned char* __restrict__ out)
{
    const int lane = threadIdx.x & 63, wid = threadIdx.x >> 6;
    const int row  = blockIdx.x * 4 + wid;
    const float4* xr = (const float4*)(x + (size_t)row * DIM);
    float4 a = xr[lane], b = xr[64 + lane];
    float s = a.x + a.y + a.z + a.w + b.x + b.y + b.z + b.w;
    float q = a.x*a.x + a.y*a.y + a.z*a.z + a.w*a.w
            + b.x*b.x + b.y*b.y + b.z*b.z + b.w*b.w;
#pragma unroll
    for (int m = 1; m < 64; m <<= 1) { s += __shfl_xor(s, m); q += __shfl_xor(q, m); }
    const float mean = s * (1.f / DIM);
    const float var  = q * (1.f / DIM) - mean * mean;
    const float rs   = rsqrtf(var + 1e-5f);
    float4 s0 = ((const float4*)sc)[lane], s1 = ((const float4*)sc)[64 + lane];
    float4 b0 = ((const float4*)bi)[lane], b1 = ((const float4*)bi)[64 + lane];
    unsigned wlo = f2e4x4((a.x - mean) * rs * s0.x + b0.x,
                          (a.y - mean) * rs * s0.y + b0.y,
                          (a.z - mean) * rs * s0.z + b0.z,
                          (a.w - mean) * rs * s0.w + b0.w);
    unsigned whi = f2e4x4((b.x - mean) * rs * s1.x + b1.x,
                          (b.y - mean) * rs * s1.y + b1.y,
                          (b.z - mean) * rs * s1.z + b1.z,
                          (b.w - mean) * rs * s1.w + b1.w);
    unsigned char* orow = out + (size_t)row * DIM;
    *(unsigned*)(orow + 4 * lane)       = wlo;
    *(unsigned*)(orow + 256 + 4 * lane) = whi;
}

// ---------------- transpose-cast fp32 (RxC) -> fp8 (CxR), x16 ----------------
__global__ __launch_bounds__(256) void tcast_f2e4_kernel(
    const float* __restrict__ in, unsigned char* __restrict__ out, int R, int C)
{
    __shared__ float t[32][33];
    const int tx = threadIdx.x & 31, ty = threadIdx.x >> 5;
    const int c0 = blockIdx.x * 32, r0 = blockIdx.y * 32;
#pragma unroll
    for (int i = 0; i < 4; ++i)
        t[ty + i * 8][tx] = in[(size_t)(r0 + ty + i * 8) * C + c0 + tx];
    __syncthreads();
#pragma unroll
    for (int i = 0; i < 4; ++i)
        out[(size_t)(c0 + ty + i * 8) * R + r0 + tx] = f2e4(t[tx][ty + i * 8] * 16.f);
}

// ---------------- fallback: out = x ----------------
__global__ __launch_bounds__(256) void copy_kernel(
    const float* __restrict__ in, float* __restrict__ out, int n4)
{
    int i = blockIdx.x * 256 + threadIdx.x;
    int stride = gridDim.x * 256;
    for (; i < n4; i += stride)
        ((float4*)out)[i] = ((const float4*)in)[i];
}

// ============ single-buffer 128x128 kernel — kept for sim (K=128, NT=1) ======
template<int EPI, int NX>
__global__ __launch_bounds__(256) void gemm8(
    const unsigned char* __restrict__ A, const unsigned char* __restrict__ B,
    int K, long strAz, long strBz, long strOz,
    const float* __restrict__ f0, const float* __restrict__ f1,
    const float* __restrict__ f2, const float* __restrict__ f3,
    const float* __restrict__ f4, const float* __restrict__ f5,
    unsigned char* __restrict__ gate,
    unsigned char* __restrict__ o0, unsigned char* __restrict__ o1,
    unsigned char* __restrict__ o2,
    float* __restrict__ fo, float scale)
{
    __shared__ unsigned char lds[32768];
    const int tid = threadIdx.x;
    const int d  = blockIdx.x + NX * blockIdx.y;
    const int qd = d >> 3;
    const int m0 = ((d & 7) + 8 * (qd / NX)) * 128;
    const int n0 = (qd % NX) * 128;
    const int z  = blockIdx.z;
    A += (size_t)z * strAz;  B += (size_t)z * strBz;
    const int lane = tid & 63, wid = tid >> 6;
    const int wm   = (wid & 1) * 64, wn = (wid >> 1) * 64;
    const int l15  = lane & 15, quad = lane >> 4;

    f32x4 acc[4][4] = {};

    const int srow = tid >> 3, sseg = tid & 7;
    const int gseg = sseg ^ (srow & 7);
    const unsigned char* gA = A + (size_t)(m0 + srow) * K + gseg * 16;
    const unsigned char* gB = B + (size_t)(n0 + srow) * K + gseg * 16;
    unsigned char* lA = lds + (size_t)tid * 16;
    unsigned char* lB = lds + 16384 + (size_t)tid * 16;

    const int olo = (((quad << 1) ^ (l15 & 7)) << 4);
    const int ohi = olo ^ 16;

    for (int kt = 0; kt < K; kt += 128) {
#pragma unroll
        for (int i = 0; i < 4; ++i)
            load16_lds(gA + (size_t)i * 32 * K + kt, lA + i * 4096);
#pragma unroll
        for (int i = 0; i < 4; ++i)
            load16_lds(gB + (size_t)i * 32 * K + kt, lB + i * 4096);
        __syncthreads();
        i32x4 alo[4], ahi[4], blo[4], bhi[4];
#pragma unroll
        for (int mi = 0; mi < 4; ++mi) {
            const unsigned char* p = lds + (wm + mi * 16 + l15) * 128;
            alo[mi] = *(const i32x4*)(p + olo); ahi[mi] = *(const i32x4*)(p + ohi);
        }
#pragma unroll
        for (int ni = 0; ni < 4; ++ni) {
            const unsigned char* p = lds + 16384 + (wn + ni * 16 + l15) * 128;
            blo[ni] = *(const i32x4*)(p + olo); bhi[ni] = *(const i32x4*)(p + ohi);
        }
#pragma unroll
        for (int mi = 0; mi < 4; ++mi) {
            i32x8 af = __builtin_shufflevector(alo[mi], ahi[mi], 0,1,2,3,4,5,6,7);
#pragma unroll
            for (int ni = 0; ni < 4; ++ni) {
                i32x8 bf = __builtin_shufflevector(blo[ni], bhi[ni], 0,1,2,3,4,5,6,7);
                acc[mi][ni] = MFMA8(af, bf, acc[mi][ni]);
            }
        }
        __syncthreads();
    }

#pragma unroll
    for (int mi = 0; mi < 4; ++mi)
#pragma unroll
    for (int ni = 0; ni < 4; ++ni) {
        const int grow0 = m0 + wm + mi * 16 + quad * 4;
        const int gcol  = n0 + wn + ni * 16 + l15;
        if constexpr (EPI == 1) {
            unsigned char* Ao = o0 + (size_t)z * strOz;
#pragma unroll
            for (int r = 0; r < 4; ++r) {
                float t = fmaxf(acc[mi][ni][r], 0.f) * 0.0625f;
                Ao[(size_t)(grow0 + r) * SEQ + gcol] = f2e4(t * t);
            }
        }
    }
}

// ====== pipelined GEMM: BM=256 x BN=128, BK=128, 8 waves, 3 LDS buffers ======
// Exact R2 structure (HW-proven 4x; VGPR=88, ledger proven against emitted
// stream). Used for EPI0 (epilogue-dominated, best measured here: 69.4 us)
// and EPI3.
template<int EPI, int NX>
__global__ __launch_bounds__(512, 2) void gemm8p(
    const unsigned char* __restrict__ A, const unsigned char* __restrict__ B,
    int K, long strAz, long strBz, long strOz,
    const float* __restrict__ f0, const float* __restrict__ f1,
    const float* __restrict__ f2, const float* __restrict__ f3,
    const float* __restrict__ f4, const float* __restrict__ f5,
    unsigned char* __restrict__ gate,
    unsigned char* __restrict__ o0, unsigned char* __restrict__ o1,
    unsigned char* __restrict__ o2,
    float* __restrict__ fo, float scale)
{
    __shared__ unsigned char lds[3 * 49152];   // per buf: A 32 KiB | B 16 KiB
    const int tid = threadIdx.x;
    const int d  = blockIdx.x + NX * blockIdx.y;
    const int qd = d >> 3;
    const int m0 = ((d & 7) + 8 * (qd / NX)) * 256;
    const int n0 = (qd % NX) * 128;
    const int z  = blockIdx.z;
    A += (size_t)z * strAz;  B += (size_t)z * strBz;
    const int lane = tid & 63, wid = tid >> 6;
    const int wm   = (wid & 3) * 64, wn = (wid >> 2) * 64;
    const int l15  = lane & 15, quad = lane >> 4;

    f32x4 acc[4][4] = {};

    const int srow = tid >> 3, sseg = tid & 7;
    const int gseg = sseg ^ (srow & 7);
    const unsigned char* gAs = A + (size_t)(m0 + srow) * K + gseg * 16;
    const unsigned char* gBs = B + (size_t)(n0 + srow) * K + gseg * 16;

    const int olo = (((quad << 1) ^ (l15 & 7)) << 4);
    const int ohi = olo ^ 16;

    const int NT = K >> 7;

    auto STAGE = [&](int t, int buf) {
        const size_t ko = (size_t)t << 7;
        unsigned char* lb = lds + buf * 49152 + tid * 16;
#pragma unroll
        for (int i = 0; i < 4; ++i)
            load16_lds(gAs + (size_t)(i * 64) * K + ko, lb + i * 8192);
#pragma unroll
        for (int i = 0; i < 2; ++i)
            load16_lds(gBs + (size_t)(i * 64) * K + ko, lb + 32768 + i * 8192);
    };

    auto COMPUTE = [&](int buf) {
        const unsigned char* la = lds + buf * 49152;
        const unsigned char* lb = la + 32768;
        i32x4 alo[4], ahi[4], blo[4], bhi[4];
#pragma unroll
        for (int mi = 0; mi < 4; ++mi) {
            const unsigned char* p = la + (size_t)(wm + mi * 16 + l15) * 128;
            alo[mi] = *(const i32x4*)(p + olo); ahi[mi] = *(const i32x4*)(p + ohi);
        }
#pragma unroll
        for (int ni = 0; ni < 4; ++ni) {
            const unsigned char* p = lb + (size_t)(wn + ni * 16 + l15) * 128;
            blo[ni] = *(const i32x4*)(p + olo); bhi[ni] = *(const i32x4*)(p + ohi);
        }
#pragma unroll
        for (int mi = 0; mi < 4; ++mi) {
            i32x8 af = __builtin_shufflevector(alo[mi], ahi[mi], 0,1,2,3,4,5,6,7);
#pragma unroll
            for (int ni = 0; ni < 4; ++ni) {
                i32x8 bf = __builtin_shufflevector(blo[ni], bhi[ni], 0,1,2,3,4,5,6,7);
                acc[mi][ni] = MFMA8(af, bf, acc[mi][ni]);
            }
        }
    };

    STAGE(0, 0);
    if (NT > 1) { STAGE(1, 1); WAITV6(); }
    else        {              WAITV0(); }
    __builtin_amdgcn_s_barrier();
    FENCE();

    int cbuf = 0, sbuf = 2;
    for (int t = 0; t < NT; ++t) {
        if (t + 2 < NT) STAGE(t + 2, sbuf);
        COMPUTE(cbuf);
        if (t + 1 < NT) {
            if (t + 2 < NT) WAITV6(); else WAITV0();
            __builtin_amdgcn_s_barrier();
            FENCE();
        }
        cbuf = (cbuf == 2) ? 0 : cbuf + 1;
        sbuf = (sbuf == 2) ? 0 : sbuf + 1;
    }

#pragma unroll
    for (int mi = 0; mi < 4; ++mi)
#pragma unroll
    for (int ni = 0; ni < 4; ++ni) {
        const int grow0 = m0 + wm + mi * 16 + quad * 4;
        const int gcol  = n0 + wn + ni * 16 + l15;
        if constexpr (EPI == 0) {
            if (gcol < HID) {
                const int b = grow0 >> 12, rloc = grow0 & (SEQ - 1);
                unsigned w = f2e4x4(silu_f(acc[mi][ni][0] * 0.0625f + f0[gcol]),
                                    silu_f(acc[mi][ni][1] * 0.0625f + f0[gcol]),
                                    silu_f(acc[mi][ni][2] * 0.0625f + f0[gcol]),
                                    silu_f(acc[mi][ni][3] * 0.0625f + f0[gcol]));
                *(unsigned*)(o0 + (size_t)b * HID * SEQ + (size_t)gcol * SEQ + rloc) = w;
            } else if (gcol < 2048) {
#pragma unroll
                for (int r = 0; r < 4; ++r)
                    gate[(size_t)(grow0 + r) * HID + (gcol - HID)] =
                        f2e4(silu_f(acc[mi][ni][r] * 0.0625f + f0[gcol]));
            } else {
                const int c = gcol - 2048;
#pragma unroll
                for (int r = 0; r < 4; ++r) {
                    float zf = silu_f(acc[mi][ni][r] * 0.0625f + f1[c]);
                    o1[(size_t)(grow0 + r) * QKD + c] = f2e4((zf * f2[c] + f4[c]) * 64.f);
                    o2[(size_t)(grow0 + r) * QKD + c] = f2e4((zf * f3[c] + f5[c]) * 64.f);
                }
            }
        } else if constexpr (EPI == 2) {
            unsigned char* gz = gate + (size_t)z * strOz;
            unsigned char* vo = o0 + (size_t)z * strOz;
#pragma unroll
            for (int r = 0; r < 4; ++r) {
                float g = e42f(gz[(size_t)(grow0 + r) * HID + gcol]);
                vo[(size_t)(grow0 + r) * HID + gcol] = f2e4(acc[mi][ni][r] * scale * g);
            }
        } else if constexpr (EPI == 3) {
#pragma unroll
            for (int r = 0; r < 4; ++r)
                fo[(size_t)(grow0 + r) * DIM + gcol] =
                    acc[mi][ni][r] * scale + f0[gcol] + f1[(size_t)(grow0 + r) * DIM + gcol];
        }
    }
}

// ====== R11: 256x256 2-buffer single-sync GEMM (A@v only) ======
// Geometry lever: wave tile 128x64 cuts LDS-port bytes/FLOP 21 -> 15.2
// (reads 192KB + writes 64KB per 2x-FLOP tile). R3 had this geometry but its
// loop-nested per-mi reads compiled to serial read->MFMA chains (5900
// cyc/tile, zero overlap). Here: R2's PROVEN COMPUTE shape — ALL fragment
// reads front-loaded into flat static-indexed locals, then all MFMAs — which
// demonstrably gets full MFMA-under-port overlap in gemm8p (3009 ~= port
// floor, MFMA hidden). Sync: ONE plain __syncthreads per tile (compiler
// vmcnt(0)+lgkmcnt(0) drain — free, since STAGE(t+1) is issued a full
// ~3000-cyc compute earlier; no manual vmcnt ledger to break).
// HW-proven (R11): A@v 80.2 -> <69.2 us, total 279.8 -> 272.5.
// NOTE (R12 lesson): does NOT transfer to short-K epilogue-heavy GEMMs
// (EPI0 regressed 69.4 -> 115 us on this structure) — long-K streaming only.
template<int EPI, int NX>
__global__ __launch_bounds__(512, 2) void gemm11(
    const unsigned char* __restrict__ A, const unsigned char* __restrict__ B,
    int K, long strAz, long strBz, long strOz,
    unsigned char* __restrict__ gate,
    unsigned char* __restrict__ o0, float scale)
{
    __shared__ unsigned char lds[2 * 65536];   // per buf: A 32 KiB | B 32 KiB
    const int tid = threadIdx.x;
    const int d  = blockIdx.x + NX * blockIdx.y;
    const int qd = d >> 3;
    const int m0 = ((d & 7) + 8 * (qd / NX)) * 256;
    const int n0 = (qd % NX) * 256;
    const int z  = blockIdx.z;
    A += (size_t)z * strAz;  B += (size_t)z * strBz;
    const int lane = tid & 63, wid = tid >> 6;
    const int wm   = (wid & 1) * 128, wn = (wid >> 1) * 64;
    const int l15  = lane & 15, quad = lane >> 4;

    f32x4 acc[8][4] = {};

    const int srow = tid >> 3, sseg = tid & 7;
    const int gseg = sseg ^ (srow & 7);
    const unsigned char* gAs = A + (size_t)(m0 + srow) * K + gseg * 16;
    const unsigned char* gBs = B + (size_t)(n0 + srow) * K + gseg * 16;

    const int olo = (((quad << 1) ^ (l15 & 7)) << 4);
    const int ohi = olo ^ 16;

    const int NT = K >> 7;

    auto STAGE = [&](int t, int buf) {
        const size_t ko = (size_t)t << 7;
        unsigned char* lb = lds + buf * 65536 + tid * 16;
#pragma unroll
        for (int i = 0; i < 4; ++i)
            load16_lds(gAs + (size_t)(i * 64) * K + ko, lb + i * 8192);
#pragma unroll
        for (int i = 0; i < 4; ++i)
            load16_lds(gBs + (size_t)(i * 64) * K + ko, lb + 32768 + i * 8192);
    };

    STAGE(0, 0);
    __syncthreads();                    // tile 0 resident (one-time exposure)

    for (int t = 0; t < NT; ++t) {
        // issue-early prefetch: lands during this tile's ~3000-cyc compute.
        // WAR safe: buf (t+1)&1 was last read in tile t-1, behind its
        // end-of-tile __syncthreads.
        if (t + 1 < NT) { STAGE(t + 1, (t + 1) & 1); FENCE(); }
        const unsigned char* la = lds + (t & 1) * 65536;
        const unsigned char* lb = la + 32768;
        // R2's proven COMPUTE shape: all 24 reads first (flat, static-indexed),
        // then all 32 MFMAs — compiler emits partial-lgkmcnt pipelining.
        i32x4 alo[8], ahi[8], blo[4], bhi[4];
#pragma unroll
        for (int mi = 0; mi < 8; ++mi) {
            const unsigned char* p = la + (size_t)(wm + mi * 16 + l15) * 128;
            alo[mi] = *(const i32x4*)(p + olo); ahi[mi] = *(const i32x4*)(p + ohi);
        }
#pragma unroll
        for (int ni = 0; ni < 4; ++ni) {
            const unsigned char* p = lb + (size_t)(wn + ni * 16 + l15) * 128;
            blo[ni] = *(const i32x4*)(p + olo); bhi[ni] = *(const i32x4*)(p + ohi);
        }
#pragma unroll
        for (int mi = 0; mi < 8; ++mi) {
            i32x8 af = __builtin_shufflevector(alo[mi], ahi[mi], 0,1,2,3,4,5,6,7);
#pragma unroll
            for (int ni = 0; ni < 4; ++ni) {
                i32x8 bf = __builtin_shufflevector(blo[ni], bhi[ni], 0,1,2,3,4,5,6,7);
                acc[mi][ni] = MFMA8(af, bf, acc[mi][ni]);
            }
        }
        if (t + 1 < NT) __syncthreads();
    }

    // C/D layout: col = lane&15, row = quad*4 + reg
#pragma unroll
    for (int mi = 0; mi < 8; ++mi)
#pragma unroll
    for (int ni = 0; ni < 4; ++ni) {
        const int grow0 = m0 + wm + mi * 16 + quad * 4;
        const int gcol  = n0 + wn + ni * 16 + l15;
        if constexpr (EPI == 2) {
            unsigned char* gz = gate + (size_t)z * strOz;
            unsigned char* vo = o0 + (size_t)z * strOz;
#pragma unroll
            for (int r = 0; r < 4; ++r) {
                float g = e42f(gz[(size_t)(grow0 + r) * HID + gcol]);
                vo[(size_t)(grow0 + r) * HID + gcol] = f2e4(acc[mi][ni][r] * scale * g);
            }
        }
    }
}

extern "C" void kernel_launch(void* const* d_in, const int* in_sizes, int n_in,
                              void* d_out, int out_size, void* d_ws, size_t ws_size,
                              hipStream_t stream) {
    const float* x     = (const float*)d_in[0];
    const float* nsc   = (const float*)d_in[1];
    const float* nbi   = (const float*)d_in[2];
    const float* Wh    = (const float*)d_in[3];
    const float* bh    = (const float*)d_in[4];
    const float* Wqk   = (const float*)d_in[5];
    const float* bqk   = (const float*)d_in[6];
    const float* gamma = (const float*)d_in[7];
    const float* beta  = (const float*)d_in[8];
    const float* Wout  = (const float*)d_in[9];
    const float* bout  = (const float*)d_in[10];
    float* out = (float*)d_out;

    uint8_t* ws = (uint8_t*)d_ws;
    size_t off = 0;
    auto alloc = [&](size_t n) { uint8_t* p = ws + off; off += (n + 255) & ~(size_t)255; return p; };
    unsigned char* normed8 = (unsigned char*)alloc((size_t)TOK * DIM);
    unsigned char* Wc8     = (unsigned char*)alloc((size_t)2176 * DIM);   // [WhT;WqkT] x16
    unsigned char* Wout8   = (unsigned char*)alloc((size_t)DIM * HID);    // x16
    unsigned char* vT8     = (unsigned char*)alloc((size_t)BAT * HID * SEQ);
    unsigned char* gbuf    = (unsigned char*)alloc((size_t)TOK * HID);    // gate fp8
    unsigned char* q8      = (unsigned char*)alloc((size_t)TOK * QKD);    // x64
    unsigned char* k8      = (unsigned char*)alloc((size_t)TOK * QKD);    // x64
    unsigned char* Ab8     = (unsigned char*)alloc((size_t)BAT * SEQ * SEQ); // x2^40
    unsigned char* vg8     = (unsigned char*)alloc((size_t)TOK * HID);    // x2^28

    if (ws_size < off) {
        copy_kernel<<<4096, 256, 0, stream>>>(x, out, TOK * DIM / 4);
        return;
    }

    ln_kernel<<<TOK / 4, 256, 0, stream>>>(x, nsc, nbi, normed8);
    tcast_f2e4_kernel<<<dim3(2048 / 32, DIM / 32), 256, 0, stream>>>(Wh, Wc8, DIM, 2048);
    tcast_f2e4_kernel<<<dim3(QKD / 32, DIM / 32), 256, 0, stream>>>(
        Wqk, Wc8 + (size_t)2048 * DIM, DIM, QKD);
    tcast_f2e4_kernel<<<dim3(DIM / 32, HID / 32), 256, 0, stream>>>(Wout, Wout8, HID, DIM);

    // hidden + qk fused: M=16384, N=2176 (17 x 128), K=512 (NT=4)
    gemm8p<0, 17><<<dim3(17, TOK / 256), 512, 0, stream>>>(
        normed8, Wc8, DIM, 0, 0, 0,
        bh, bqk, gamma, gamma + QKD, beta, beta + QKD,
        gbuf, vT8, q8, k8, nullptr, 0.f);

    // sim: K = 128 (single slab, no pipeline) -> keep 128x128 kernel
    gemm8<1, 32><<<dim3(SEQ / 128, SEQ / 128, BAT), 256, 0, stream>>>(
        q8, k8, QKD, (long)SEQ * QKD, (long)SEQ * QKD, (long)SEQ * SEQ,
        nullptr, nullptr, nullptr, nullptr, nullptr, nullptr,
        nullptr, Ab8, nullptr, nullptr, nullptr, 0.f);

    // A@v: M=4096/z, N=1024, K=4096 (NT=32), z-batched; vg8 = acc*2^-12*gate
    // gemm11: 256x256 tiles, grid 4 x 16 x 4 = 256 blocks = one GPU round
    gemm11<2, 4><<<dim3(HID / 256, SEQ / 256, BAT), 512, 0, stream>>>(
        Ab8, vT8, SEQ, (long)SEQ * SEQ, (long)HID * SEQ, (long)SEQ * HID,
        gbuf, vg8, 0x1p-12f);

    // out: M=16384, N=512, K=1024 (NT=8); out = acc*2^-32 + b_out + x
    gemm8p<3, 4><<<dim3(DIM / 128, TOK / 256), 512, 0, stream>>>(
        vg8, Wout8, HID, 0, 0, 0,
        bout, x, nullptr, nullptr, nullptr, nullptr,
        nullptr, nullptr, nullptr, nullptr, out, 0x1p-32f);
}

// Round 14
// 271.677 us; speedup vs baseline: 1.1493x; 1.0101x over previous
//
#include <hip/hip_runtime.h>
#include <cstdint>
#include <cstddef>

#define DIM   512
#define QKD   128
#define HID   1024
#define SEQ   4096
#define BAT   4
#define TOK   (BAT*SEQ)

typedef float f32x4 __attribute__((ext_vector_type(4)));
typedef int   i32x4 __attribute__((ext_vector_type(4)));
typedef int   i32x8 __attribute__((ext_vector_type(8)));

__device__ __forceinline__ float silu_f(float x) { return x / (1.f + __expf(-x)); }

__device__ __forceinline__ unsigned char f2e4(float f) {
    int v = __builtin_amdgcn_cvt_pk_fp8_f32(f, 0.f, 0, false);
    return (unsigned char)(v & 0xff);
}
__device__ __forceinline__ unsigned f2e4x4(float a, float b, float c, float d) {
    int w = __builtin_amdgcn_cvt_pk_fp8_f32(a, b, 0, false);
    w = __builtin_amdgcn_cvt_pk_fp8_f32(c, d, w, true);
    return (unsigned)w;
}
__device__ __forceinline__ float e42f(unsigned char b) {
    return __builtin_amdgcn_cvt_f32_fp8((int)b, 0);
}

__device__ __forceinline__ void load16_lds(const void* gp, void* lp) {
    __builtin_amdgcn_global_load_lds(
        (const __attribute__((address_space(1))) unsigned int*)gp,
        (__attribute__((address_space(3))) unsigned int*)lp,
        16, 0, 0);
}

#define WAITV6() asm volatile("s_waitcnt vmcnt(6)" ::: "memory")
#define WAITV0() asm volatile("s_waitcnt vmcnt(0)" ::: "memory")
#define FENCE()  do { asm volatile("" ::: "memory"); __builtin_amdgcn_sched_barrier(0); } while (0)

#define MFMA8(af, bf, c) __builtin_amdgcn_mfma_scale_f32_16x16x128_f8f6f4( \
    af, bf, c, 0, 0, 0, 0x7F7F7F7F, 0, 0x7F7F7F7F)

// ---------------- LayerNorm: fp32 x -> fp8 normed ----------------
__global__ __launch_bounds__(256) void ln_kernel(
    const float* __restrict__ x, const float* __restrict__ sc,
    const float* __restrict__ bi, unsigned char* __restrict__ out)
{
    const int lane = threadIdx.x & 63, wid = threadIdx.x >> 6;
    const int row  = blockIdx.x * 4 + wid;
    const float4* xr = (const float4*)(x + (size_t)row * DIM);
    float4 a = xr[lane], b = xr[64 + lane];
    float s = a.x + a.y + a.z + a.w + b.x + b.y + b.z + b.w;
    float q = a.x*a.x + a.y*a.y + a.z*a.z + a.w*a.w
            + b.x*b.x + b.y*b.y + b.z*b.z + b.w*b.w;
#pragma unroll
    for (int m = 1; m < 64; m <<= 1) { s += __shfl_xor(s, m); q += __shfl_xor(q, m); }
    const float mean = s * (1.f / DIM);
    const float var  = q * (1.f / DIM) - mean * mean;
    const float rs   = rsqrtf(var + 1e-5f);
    float4 s0 = ((const float4*)sc)[lane], s1 = ((const float4*)sc)[64 + lane];
    float4 b0 = ((const float4*)bi)[lane], b1 = ((const float4*)bi)[64 + lane];
    unsigned wlo = f2e4x4((a.x - mean) * rs * s0.x + b0.x,
                          (a.y - mean) * rs * s0.y + b0.y,
                          (a.z - mean) * rs * s0.z + b0.z,
                          (a.w - mean) * rs * s0.w + b0.w);
    unsigned whi = f2e4x4((b.x - mean) * rs * s1.x + b1.x,
                          (b.y - mean) * rs * s1.y + b1.y,
                          (b.z - mean) * rs * s1.z + b1.z,
                          (b.w - mean) * rs * s1.w + b1.w);
    unsigned char* orow = out + (size_t)row * DIM;
    *(unsigned*)(orow + 4 * lane)       = wlo;
    *(unsigned*)(orow + 256 + 4 * lane) = whi;
}

// ---------------- transpose-cast fp32 (RxC) -> fp8 (CxR), x16 ----------------
__global__ __launch_bounds__(256) void tcast_f2e4_kernel(
    const float* __restrict__ in, unsigned char* __restrict__ out, int R, int C)
{
    __shared__ float t[32][33];
    const int tx = threadIdx.x & 31, ty = threadIdx.x >> 5;
    const int c0 = blockIdx.x * 32, r0 = blockIdx.y * 32;
#pragma unroll
    for (int i = 0; i < 4; ++i)
        t[ty + i * 8][tx] = in[(size_t)(r0 + ty + i * 8) * C + c0 + tx];
    __syncthreads();
#pragma unroll
    for (int i = 0; i < 4; ++i)
        out[(size_t)(c0 + ty + i * 8) * R + r0 + tx] = f2e4(t[tx][ty + i * 8] * 16.f);
}

// ---------------- fallback: out = x ----------------
__global__ __launch_bounds__(256) void copy_kernel(
    const float* __restrict__ in, float* __restrict__ out, int n4)
{
    int i = blockIdx.x * 256 + threadIdx.x;
    int stride = gridDim.x * 256;
    for (; i < n4; i += stride)
        ((float4*)out)[i] = ((const float4*)in)[i];
}

// ============ single-buffer 128x128 kernel — kept for sim (K=128, NT=1) ======
template<int EPI, int NX>
__global__ __launch_bounds__(256) void gemm8(
    const unsigned char* __restrict__ A, const unsigned char* __restrict__ B,
    int K, long strAz, long strBz, long strOz,
    const float* __restrict__ f0, const float* __restrict__ f1,
    const float* __restrict__ f2, const float* __restrict__ f3,
    const float* __restrict__ f4, const float* __restrict__ f5,
    unsigned char* __restrict__ gate,
    unsigned char* __restrict__ o0, unsigned char* __restrict__ o1,
    unsigned char* __restrict__ o2,
    float* __restrict__ fo, float scale)
{
    __shared__ unsigned char lds[32768];
    const int tid = threadIdx.x;
    const int d  = blockIdx.x + NX * blockIdx.y;
    const int qd = d >> 3;
    const int m0 = ((d & 7) + 8 * (qd / NX)) * 128;
    const int n0 = (qd % NX) * 128;
    const int z  = blockIdx.z;
    A += (size_t)z * strAz;  B += (size_t)z * strBz;
    const int lane = tid & 63, wid = tid >> 6;
    const int wm   = (wid & 1) * 64, wn = (wid >> 1) * 64;
    const int l15  = lane & 15, quad = lane >> 4;

    f32x4 acc[4][4] = {};

    const int srow = tid >> 3, sseg = tid & 7;
    const int gseg = sseg ^ (srow & 7);
    const unsigned char* gA = A + (size_t)(m0 + srow) * K + gseg * 16;
    const unsigned char* gB = B + (size_t)(n0 + srow) * K + gseg * 16;
    unsigned char* lA = lds + (size_t)tid * 16;
    unsigned char* lB = lds + 16384 + (size_t)tid * 16;

    const int olo = (((quad << 1) ^ (l15 & 7)) << 4);
    const int ohi = olo ^ 16;

    for (int kt = 0; kt < K; kt += 128) {
#pragma unroll
        for (int i = 0; i < 4; ++i)
            load16_lds(gA + (size_t)i * 32 * K + kt, lA + i * 4096);
#pragma unroll
        for (int i = 0; i < 4; ++i)
            load16_lds(gB + (size_t)i * 32 * K + kt, lB + i * 4096);
        __syncthreads();
        i32x4 alo[4], ahi[4], blo[4], bhi[4];
#pragma unroll
        for (int mi = 0; mi < 4; ++mi) {
            const unsigned char* p = lds + (wm + mi * 16 + l15) * 128;
            alo[mi] = *(const i32x4*)(p + olo); ahi[mi] = *(const i32x4*)(p + ohi);
        }
#pragma unroll
        for (int ni = 0; ni < 4; ++ni) {
            const unsigned char* p = lds + 16384 + (wn + ni * 16 + l15) * 128;
            blo[ni] = *(const i32x4*)(p + olo); bhi[ni] = *(const i32x4*)(p + ohi);
        }
#pragma unroll
        for (int mi = 0; mi < 4; ++mi) {
            i32x8 af = __builtin_shufflevector(alo[mi], ahi[mi], 0,1,2,3,4,5,6,7);
#pragma unroll
            for (int ni = 0; ni < 4; ++ni) {
                i32x8 bf = __builtin_shufflevector(blo[ni], bhi[ni], 0,1,2,3,4,5,6,7);
                acc[mi][ni] = MFMA8(af, bf, acc[mi][ni]);
            }
        }
        __syncthreads();
    }

#pragma unroll
    for (int mi = 0; mi < 4; ++mi)
#pragma unroll
    for (int ni = 0; ni < 4; ++ni) {
        const int grow0 = m0 + wm + mi * 16 + quad * 4;
        const int gcol  = n0 + wn + ni * 16 + l15;
        if constexpr (EPI == 1) {
            unsigned char* Ao = o0 + (size_t)z * strOz;
#pragma unroll
            for (int r = 0; r < 4; ++r) {
                float t = fmaxf(acc[mi][ni][r], 0.f) * 0.0625f;
                Ao[(size_t)(grow0 + r) * SEQ + gcol] = f2e4(t * t);
            }
        }
    }
}

// ====== pipelined GEMM: BM=256 x BN=128, BK=128, 8 waves, 3 LDS buffers ======
// Exact R2 K-loop (HW-proven 4x; VGPR=88, ledger proven against emitted
// stream). R14: EPI0 pure-vT8 blocks (n0<HID, block-uniform) stage the
// transposed output through the now-free LDS and store cooperatively —
// 16-segment scattered wave-stores become 4x 256B-row stores. K-loop and
// all other epilogues untouched.
template<int EPI, int NX>
__global__ __launch_bounds__(512, 2) void gemm8p(
    const unsigned char* __restrict__ A, const unsigned char* __restrict__ B,
    int K, long strAz, long strBz, long strOz,
    const float* __restrict__ f0, const float* __restrict__ f1,
    const float* __restrict__ f2, const float* __restrict__ f3,
    const float* __restrict__ f4, const float* __restrict__ f5,
    unsigned char* __restrict__ gate,
    unsigned char* __restrict__ o0, unsigned char* __restrict__ o1,
    unsigned char* __restrict__ o2,
    float* __restrict__ fo, float scale)
{
    __shared__ unsigned char lds[3 * 49152];   // per buf: A 32 KiB | B 16 KiB
    const int tid = threadIdx.x;
    const int d  = blockIdx.x + NX * blockIdx.y;
    const int qd = d >> 3;
    const int m0 = ((d & 7) + 8 * (qd / NX)) * 256;
    const int n0 = (qd % NX) * 128;
    const int z  = blockIdx.z;
    A += (size_t)z * strAz;  B += (size_t)z * strBz;
    const int lane = tid & 63, wid = tid >> 6;
    const int wm   = (wid & 3) * 64, wn = (wid >> 2) * 64;
    const int l15  = lane & 15, quad = lane >> 4;

    f32x4 acc[4][4] = {};

    const int srow = tid >> 3, sseg = tid & 7;
    const int gseg = sseg ^ (srow & 7);
    const unsigned char* gAs = A + (size_t)(m0 + srow) * K + gseg * 16;
    const unsigned char* gBs = B + (size_t)(n0 + srow) * K + gseg * 16;

    const int olo = (((quad << 1) ^ (l15 & 7)) << 4);
    const int ohi = olo ^ 16;

    const int NT = K >> 7;

    auto STAGE = [&](int t, int buf) {
        const size_t ko = (size_t)t << 7;
        unsigned char* lb = lds + buf * 49152 + tid * 16;
#pragma unroll
        for (int i = 0; i < 4; ++i)
            load16_lds(gAs + (size_t)(i * 64) * K + ko, lb + i * 8192);
#pragma unroll
        for (int i = 0; i < 2; ++i)
            load16_lds(gBs + (size_t)(i * 64) * K + ko, lb + 32768 + i * 8192);
    };

    auto COMPUTE = [&](int buf) {
        const unsigned char* la = lds + buf * 49152;
        const unsigned char* lb = la + 32768;
        i32x4 alo[4], ahi[4], blo[4], bhi[4];
#pragma unroll
        for (int mi = 0; mi < 4; ++mi) {
            const unsigned char* p = la + (size_t)(wm + mi * 16 + l15) * 128;
            alo[mi] = *(const i32x4*)(p + olo); ahi[mi] = *(const i32x4*)(p + ohi);
        }
#pragma unroll
        for (int ni = 0; ni < 4; ++ni) {
            const unsigned char* p = lb + (size_t)(wn + ni * 16 + l15) * 128;
            blo[ni] = *(const i32x4*)(p + olo); bhi[ni] = *(const i32x4*)(p + ohi);
        }
#pragma unroll
        for (int mi = 0; mi < 4; ++mi) {
            i32x8 af = __builtin_shufflevector(alo[mi], ahi[mi], 0,1,2,3,4,5,6,7);
#pragma unroll
            for (int ni = 0; ni < 4; ++ni) {
                i32x8 bf = __builtin_shufflevector(blo[ni], bhi[ni], 0,1,2,3,4,5,6,7);
                acc[mi][ni] = MFMA8(af, bf, acc[mi][ni]);
            }
        }
    };

    STAGE(0, 0);
    if (NT > 1) { STAGE(1, 1); WAITV6(); }
    else        {              WAITV0(); }
    __builtin_amdgcn_s_barrier();
    FENCE();

    int cbuf = 0, sbuf = 2;
    for (int t = 0; t < NT; ++t) {
        if (t + 2 < NT) STAGE(t + 2, sbuf);
        COMPUTE(cbuf);
        if (t + 1 < NT) {
            if (t + 2 < NT) WAITV6(); else WAITV0();
            __builtin_amdgcn_s_barrier();
            FENCE();
        }
        cbuf = (cbuf == 2) ? 0 : cbuf + 1;
        sbuf = (sbuf == 2) ? 0 : sbuf + 1;
    }

    if constexpr (EPI == 0) {
        if (n0 < HID) {
            // ---- pure vT8 block: LDS-staged transposed store ----
            // All waves finished their LDS fragment reads (lgkmcnt before
            // their MFMAs), so after this barrier LDS is reusable.
            __syncthreads();
            unsigned* lw = (unsigned*)lds;   // [128 c][64 words] = 32 KiB
#pragma unroll
            for (int mi = 0; mi < 4; ++mi)
#pragma unroll
            for (int ni = 0; ni < 4; ++ni) {
                const int c  = wn + ni * 16 + l15;
                const int mw = (wm >> 2) + mi * 4 + quad;   // word idx 0..63
                const float bias = f0[n0 + c];
                unsigned w = f2e4x4(silu_f(acc[mi][ni][0] * 0.0625f + bias),
                                    silu_f(acc[mi][ni][1] * 0.0625f + bias),
                                    silu_f(acc[mi][ni][2] * 0.0625f + bias),
                                    silu_f(acc[mi][ni][3] * 0.0625f + bias));
                // XOR swizzle keeps low-2 bits -> x4 read stays contiguous;
                // write banks 2-way (free), read banks 2-way (free).
                lw[c * 64 + (mw ^ ((c & 15) << 2))] = w;
            }
            __syncthreads();
            const int bb = m0 >> 12, rl = m0 & (SEQ - 1);
            unsigned char* dst0 = o0 + (size_t)bb * HID * SEQ
                                     + (size_t)n0 * SEQ + rl;
#pragma unroll
            for (int k = 0; k < 4; ++k) {
                const int idx = tid + k * 512;        // 0..2047
                const int c = idx >> 4, j = idx & 15; // row c, 16B chunk j
                const unsigned* src = lw + c * 64 + ((j * 4) ^ ((c & 15) << 2));
                *(i32x4*)(dst0 + (size_t)c * SEQ + j * 16) = *(const i32x4*)src;
            }
        } else {
            // ---- gate / qk blocks: original per-element path ----
#pragma unroll
            for (int mi = 0; mi < 4; ++mi)
#pragma unroll
            for (int ni = 0; ni < 4; ++ni) {
                const int grow0 = m0 + wm + mi * 16 + quad * 4;
                const int gcol  = n0 + wn + ni * 16 + l15;
                if (gcol < 2048) {
#pragma unroll
                    for (int r = 0; r < 4; ++r)
                        gate[(size_t)(grow0 + r) * HID + (gcol - HID)] =
                            f2e4(silu_f(acc[mi][ni][r] * 0.0625f + f0[gcol]));
                } else {
                    const int c = gcol - 2048;
#pragma unroll
                    for (int r = 0; r < 4; ++r) {
                        float zf = silu_f(acc[mi][ni][r] * 0.0625f + f1[c]);
                        o1[(size_t)(grow0 + r) * QKD + c] = f2e4((zf * f2[c] + f4[c]) * 64.f);
                        o2[(size_t)(grow0 + r) * QKD + c] = f2e4((zf * f3[c] + f5[c]) * 64.f);
                    }
                }
            }
        }
    } else {
#pragma unroll
        for (int mi = 0; mi < 4; ++mi)
#pragma unroll
        for (int ni = 0; ni < 4; ++ni) {
            const int grow0 = m0 + wm + mi * 16 + quad * 4;
            const int gcol  = n0 + wn + ni * 16 + l15;
            if constexpr (EPI == 2) {
                unsigned char* gz = gate + (size_t)z * strOz;
                unsigned char* vo = o0 + (size_t)z * strOz;
#pragma unroll
                for (int r = 0; r < 4; ++r) {
                    float g = e42f(gz[(size_t)(grow0 + r) * HID + gcol]);
                    vo[(size_t)(grow0 + r) * HID + gcol] = f2e4(acc[mi][ni][r] * scale * g);
                }
            } else if constexpr (EPI == 3) {
#pragma unroll
                for (int r = 0; r < 4; ++r)
                    fo[(size_t)(grow0 + r) * DIM + gcol] =
                        acc[mi][ni][r] * scale + f0[gcol] + f1[(size_t)(grow0 + r) * DIM + gcol];
            }
        }
    }
}

// ====== R11: 256x256 2-buffer single-sync GEMM (A@v only, HW-proven) ======
template<int EPI, int NX>
__global__ __launch_bounds__(512, 2) void gemm11(
    const unsigned char* __restrict__ A, const unsigned char* __restrict__ B,
    int K, long strAz, long strBz, long strOz,
    unsigned char* __restrict__ gate,
    unsigned char* __restrict__ o0, float scale)
{
    __shared__ unsigned char lds[2 * 65536];   // per buf: A 32 KiB | B 32 KiB
    const int tid = threadIdx.x;
    const int d  = blockIdx.x + NX * blockIdx.y;
    const int qd = d >> 3;
    const int m0 = ((d & 7) + 8 * (qd / NX)) * 256;
    const int n0 = (qd % NX) * 256;
    const int z  = blockIdx.z;
    A += (size_t)z * strAz;  B += (size_t)z * strBz;
    const int lane = tid & 63, wid = tid >> 6;
    const int wm   = (wid & 1) * 128, wn = (wid >> 1) * 64;
    const int l15  = lane & 15, quad = lane >> 4;

    f32x4 acc[8][4] = {};

    const int srow = tid >> 3, sseg = tid & 7;
    const int gseg = sseg ^ (srow & 7);
    const unsigned char* gAs = A + (size_t)(m0 + srow) * K + gseg * 16;
    const unsigned char* gBs = B + (size_t)(n0 + srow) * K + gseg * 16;

    const int olo = (((quad << 1) ^ (l15 & 7)) << 4);
    const int ohi = olo ^ 16;

    const int NT = K >> 7;

    auto STAGE = [&](int t, int buf) {
        const size_t ko = (size_t)t << 7;
        unsigned char* lb = lds + buf * 65536 + tid * 16;
#pragma unroll
        for (int i = 0; i < 4; ++i)
            load16_lds(gAs + (size_t)(i * 64) * K + ko, lb + i * 8192);
#pragma unroll
        for (int i = 0; i < 4; ++i)
            load16_lds(gBs + (size_t)(i * 64) * K + ko, lb + 32768 + i * 8192);
    };

    STAGE(0, 0);
    __syncthreads();                    // tile 0 resident (one-time exposure)

    for (int t = 0; t < NT; ++t) {
        if (t + 1 < NT) { STAGE(t + 1, (t + 1) & 1); FENCE(); }
        const unsigned char* la = lds + (t & 1) * 65536;
        const unsigned char* lb = la + 32768;
        i32x4 alo[8], ahi[8], blo[4], bhi[4];
#pragma unroll
        for (int mi = 0; mi < 8; ++mi) {
            const unsigned char* p = la + (size_t)(wm + mi * 16 + l15) * 128;
            alo[mi] = *(const i32x4*)(p + olo); ahi[mi] = *(const i32x4*)(p + ohi);
        }
#pragma unroll
        for (int ni = 0; ni < 4; ++ni) {
            const unsigned char* p = lb + (size_t)(wn + ni * 16 + l15) * 128;
            blo[ni] = *(const i32x4*)(p + olo); bhi[ni] = *(const i32x4*)(p + ohi);
        }
#pragma unroll
        for (int mi = 0; mi < 8; ++mi) {
            i32x8 af = __builtin_shufflevector(alo[mi], ahi[mi], 0,1,2,3,4,5,6,7);
#pragma unroll
            for (int ni = 0; ni < 4; ++ni) {
                i32x8 bf = __builtin_shufflevector(blo[ni], bhi[ni], 0,1,2,3,4,5,6,7);
                acc[mi][ni] = MFMA8(af, bf, acc[mi][ni]);
            }
        }
        if (t + 1 < NT) __syncthreads();
    }

    // C/D layout: col = lane&15, row = quad*4 + reg
#pragma unroll
    for (int mi = 0; mi < 8; ++mi)
#pragma unroll
    for (int ni = 0; ni < 4; ++ni) {
        const int grow0 = m0 + wm + mi * 16 + quad * 4;
        const int gcol  = n0 + wn + ni * 16 + l15;
        if constexpr (EPI == 2) {
            unsigned char* gz = gate + (size_t)z * strOz;
            unsigned char* vo = o0 + (size_t)z * strOz;
#pragma unroll
            for (int r = 0; r < 4; ++r) {
                float g = e42f(gz[(size_t)(grow0 + r) * HID + gcol]);
                vo[(size_t)(grow0 + r) * HID + gcol] = f2e4(acc[mi][ni][r] * scale * g);
            }
        }
    }
}

extern "C" void kernel_launch(void* const* d_in, const int* in_sizes, int n_in,
                              void* d_out, int out_size, void* d_ws, size_t ws_size,
                              hipStream_t stream) {
    const float* x     = (const float*)d_in[0];
    const float* nsc   = (const float*)d_in[1];
    const float* nbi   = (const float*)d_in[2];
    const float* Wh    = (const float*)d_in[3];
    const float* bh    = (const float*)d_in[4];
    const float* Wqk   = (const float*)d_in[5];
    const float* bqk   = (const float*)d_in[6];
    const float* gamma = (const float*)d_in[7];
    const float* beta  = (const float*)d_in[8];
    const float* Wout  = (const float*)d_in[9];
    const float* bout  = (const float*)d_in[10];
    float* out = (float*)d_out;

    uint8_t* ws = (uint8_t*)d_ws;
    size_t off = 0;
    auto alloc = [&](size_t n) { uint8_t* p = ws + off; off += (n + 255) & ~(size_t)255; return p; };
    unsigned char* normed8 = (unsigned char*)alloc((size_t)TOK * DIM);
    unsigned char* Wc8     = (unsigned char*)alloc((size_t)2176 * DIM);   // [WhT;WqkT] x16
    unsigned char* Wout8   = (unsigned char*)alloc((size_t)DIM * HID);    // x16
    unsigned char* vT8     = (unsigned char*)alloc((size_t)BAT * HID * SEQ);
    unsigned char* gbuf    = (unsigned char*)alloc((size_t)TOK * HID);    // gate fp8
    unsigned char* q8      = (unsigned char*)alloc((size_t)TOK * QKD);    // x64
    unsigned char* k8      = (unsigned char*)alloc((size_t)TOK * QKD);    // x64
    unsigned char* Ab8     = (unsigned char*)alloc((size_t)BAT * SEQ * SEQ); // x2^40
    unsigned char* vg8     = (unsigned char*)alloc((size_t)TOK * HID);    // x2^28

    if (ws_size < off) {
        copy_kernel<<<4096, 256, 0, stream>>>(x, out, TOK * DIM / 4);
        return;
    }

    ln_kernel<<<TOK / 4, 256, 0, stream>>>(x, nsc, nbi, normed8);
    tcast_f2e4_kernel<<<dim3(2048 / 32, DIM / 32), 256, 0, stream>>>(Wh, Wc8, DIM, 2048);
    tcast_f2e4_kernel<<<dim3(QKD / 32, DIM / 32), 256, 0, stream>>>(
        Wqk, Wc8 + (size_t)2048 * DIM, DIM, QKD);
    tcast_f2e4_kernel<<<dim3(DIM / 32, HID / 32), 256, 0, stream>>>(Wout, Wout8, HID, DIM);

    // hidden + qk fused: M=16384, N=2176 (17 x 128), K=512 (NT=4)
    gemm8p<0, 17><<<dim3(17, TOK / 256), 512, 0, stream>>>(
        normed8, Wc8, DIM, 0, 0, 0,
        bh, bqk, gamma, gamma + QKD, beta, beta + QKD,
        gbuf, vT8, q8, k8, nullptr, 0.f);

    // sim: K = 128 (single slab, no pipeline) -> keep 128x128 kernel
    gemm8<1, 32><<<dim3(SEQ / 128, SEQ / 128, BAT), 256, 0, stream>>>(
        q8, k8, QKD, (long)SEQ * QKD, (long)SEQ * QKD, (long)SEQ * SEQ,
        nullptr, nullptr, nullptr, nullptr, nullptr, nullptr,
        nullptr, Ab8, nullptr, nullptr, nullptr, 0.f);

    // A@v: M=4096/z, N=1024, K=4096 (NT=32), z-batched; vg8 = acc*2^-12*gate
    gemm11<2, 4><<<dim3(HID / 256, SEQ / 256, BAT), 512, 0, stream>>>(
        Ab8, vT8, SEQ, (long)SEQ * SEQ, (long)HID * SEQ, (long)SEQ * HID,
        gbuf, vg8, 0x1p-12f);

    // out: M=16384, N=512, K=1024 (NT=8); out = acc*2^-32 + b_out + x
    gemm8p<3, 4><<<dim3(DIM / 128, TOK / 256), 512, 0, stream>>>(
        vg8, Wout8, HID, 0, 0, 0,
        bout, x, nullptr, nullptr, nullptr, nullptr,
        nullptr, nullptr, nullptr, nullptr, out, 0x1p-32f);
}